// Round 1
// 241.269 us; speedup vs baseline: 1.0994x; 1.0994x over previous
//
#include <hip/hip_runtime.h>

#define E_EDGES   1000000
#define NNODES    2048
#define DLAT      64
#define HCH       128
#define KP        168            // LDS row stride in bf16 elements (84 dwords: 8-bank cycle, 2-way = free)
#define TILE      64
#define NTILES    (E_EDGES / TILE)   // 15625 exact
#define NSPREAD   8
#define GRID_GEMM 2048
#define ZVEC      (32 * 2048 * 64 / 4)   // 1048576 float4s
#define ZBLK      2048

typedef short  shortx8 __attribute__((ext_vector_type(8)));
typedef float  floatx4 __attribute__((ext_vector_type(4)));

__device__ __forceinline__ unsigned short f2bf(float f) {
  union { float f; unsigned int u; } v; v.f = f;
  unsigned int r = (v.u + 0x7fffu + ((v.u >> 16) & 1u)) >> 16;
  return (unsigned short)r;
}

__device__ __forceinline__ void cfence() { asm volatile("" ::: "memory"); }
// Producer barrier: drain LDS ops (writes visible to all waves), raw s_barrier.
// Crucially does NOT drain vmcnt — in-flight global prefetches survive the barrier.
__device__ __forceinline__ void bar_lds() {
  asm volatile("s_waitcnt lgkmcnt(0)" ::: "memory");
  __builtin_amdgcn_s_barrier();
  cfence();
}

// ---------------------------------------------------------------- prep ----
__global__ void k_prep(const float* __restrict__ z, const float* __restrict__ W1,
                       const float* __restrict__ b1,
                       unsigned short* __restrict__ zb, unsigned short* __restrict__ w1t,
                       float* __restrict__ gstats) {
  int bid = blockIdx.x;
  if (bid < ZBLK) {
    const float4* z4 = (const float4*)z;
    ushort4* zb4 = (ushort4*)zb;
    for (int i = bid * 256 + threadIdx.x; i < ZVEC; i += ZBLK * 256) {
      float4 v = z4[i];
      ushort4 o;
      o.x = f2bf(v.x); o.y = f2bf(v.y); o.z = f2bf(v.z); o.w = f2bf(v.w);
      zb4[i] = o;
    }
  } else if (bid == ZBLK) {
    // W1T[n][k] = W1[k][n] for k<132, b1[n] at k=132, 0 for k in 133..167
    for (int idx = threadIdx.x; idx < 132 * HCH; idx += 256) {
      int k = idx >> 7, n = idx & 127;              // coalesced read of W1
      w1t[n * KP + k] = f2bf(W1[idx]);
    }
    for (int idx = threadIdx.x; idx < HCH * (KP - 132); idx += 256) {
      int n = idx / (KP - 132);
      int k = 132 + (idx - n * (KP - 132));
      w1t[n * KP + k] = (k == 132) ? f2bf(b1[n]) : (unsigned short)0;
    }
  } else {
    for (int i = threadIdx.x; i < NSPREAD * 2 * HCH; i += 256) gstats[i] = 0.f;
  }
}

// ---------------------------------------------------------------- gemm ----
// Pipelined: LDS-double-buffered A, register prefetch of next tile's gather
// (indices prefetched two tiles ahead), one producer barrier per tile.
// 4 waves in 2x2: wave=(eh,nh) covers edges eh*32..+31, channels nh*64..+63.
// B fragments (W1T) live in registers for the whole kernel.
template<bool OUT>
__global__ __launch_bounds__(256, 2)
void k_gemm(const unsigned short* __restrict__ zb,
            const unsigned short* __restrict__ w1t,
            const int* __restrict__ ei,
            const float* __restrict__ attr,
            float* __restrict__ gstats,
            const float* __restrict__ gamma,
            const float* __restrict__ beta,
            const float* __restrict__ W2,
            const float* __restrict__ b2,
            float* __restrict__ out) {
  __shared__ __align__(16) unsigned short A[2 * TILE * KP];   // 43008 B (double buffer)
  __shared__ float s_sum[HCH], s_sq[HCH];
  __shared__ float po[TILE];

  const int tid  = threadIdx.x;
  const int lane = tid & 63;
  const int wave = tid >> 6;
  const int l15  = lane & 15;
  const int quad = lane >> 4;
  const int eh   = wave >> 1;
  const int nh   = wave & 1;
  const int e    = tid >> 2;     // edge within tile handled by this thread
  const int q    = tid & 3;      // quarter: 0,1 = src row halves; 2,3 = dst row halves
  const int grid = GRID_GEMM;

  // ---- B fragments in registers: b[nt][kk], n = nh*64 + nt*16 + l15
  shortx8 bfr[4][5];
#pragma unroll
  for (int nt = 0; nt < 4; ++nt) {
    const unsigned short* bp = w1t + (nh * 64 + nt * 16 + l15) * KP + quad * 8;
#pragma unroll
    for (int kk = 0; kk < 5; ++kk)
      bfr[nt][kk] = *(const shortx8*)(bp + kk * 32);
  }

  float ea[4], ebb[4], ew2[4], b2v = 0.f;
  float ssum[4] = {0.f, 0.f, 0.f, 0.f}, ssq[4] = {0.f, 0.f, 0.f, 0.f};
  if (OUT) {
    // fold the old k_final in: derive BN affine from gstats per block
#pragma unroll
    for (int nt = 0; nt < 4; ++nt) {
      int c = nh * 64 + nt * 16 + l15;
      float S = 0.f, Q = 0.f;
#pragma unroll
      for (int i = 0; i < NSPREAD; ++i) {
        S += gstats[i * 2 * HCH + c];
        Q += gstats[i * 2 * HCH + HCH + c];
      }
      float mu   = S * (1.0f / (float)E_EDGES);
      float var  = Q * (1.0f / (float)E_EDGES) - mu * mu;
      float rstd = rsqrtf(var + 1e-5f);
      float a = gamma[c] * rstd;
      ea[nt]  = a;
      ebb[nt] = beta[c] - mu * a;
      ew2[nt] = W2[c];
    }
    b2v = b2[0];
  } else {
    if (tid < HCH) { s_sum[tid] = 0.f; s_sq[tid] = 0.f; }
  }

  // ---- constant K-pad (elements 132..167: bias=1.0 then zeros), both buffers, once
  {
    ushort4 bl; bl.x = 0x3F80; bl.y = 0; bl.z = 0; bl.w = 0;
    uint4 zed = {0, 0, 0, 0};
#pragma unroll
    for (int b = 0; b < 2; ++b) {
      unsigned short* rp = A + b * (TILE * KP) + e * KP;
      if (q == 0) *(ushort4*)(rp + 132) = bl;
      *(uint4*)(rp + 136 + q * 8) = zed;
    }
  }

  // ---- software-pipeline prologue: stage t0 into buf0, prefetch gather(t1), ei(t2)
  const int t0 = blockIdx.x;
  int tc1 = t0 + grid;  if (tc1 > NTILES - 1) tc1 = NTILES - 1;
  int tc2 = tc1 + grid; if (tc2 > NTILES - 1) tc2 = NTILES - 1;

  uint4 g0, g1, g2, g3;   // prefetched z-gather (64 B/thread)
  float4 av;              // prefetched attr (wave 0 only)
  int s2, d2;             // prefetched edge indices, two tiles ahead
  {
    int s0 = ei[t0 * TILE + e];
    int d0 = ei[E_EDGES + t0 * TILE + e];
    int r0 = (q < 2) ? s0 : ((s0 & ~(NNODES - 1)) | (d0 & (NNODES - 1)));  // dst uses src batch
    const uint4* sp = (const uint4*)(zb + r0 * DLAT + (q & 1) * 32);
    g0 = sp[0]; g1 = sp[1]; g2 = sp[2]; g3 = sp[3];
    if (wave == 0) av = ((const float4*)attr)[t0 * TILE + tid];
    s2 = ei[tc1 * TILE + e];
    d2 = ei[E_EDGES + tc1 * TILE + e];
    // stage tile t0 into buffer 0
    uint4* dst = (uint4*)(A + e * KP + q * 32);
    dst[0] = g0; dst[1] = g1; dst[2] = g2; dst[3] = g3;
    if (wave == 0) {
      ushort4 a0; a0.x = f2bf(av.x); a0.y = f2bf(av.y); a0.z = f2bf(av.z); a0.w = f2bf(av.w);
      *(ushort4*)(A + tid * KP + 128) = a0;
    }
    // prefetch gather(t1) + attr(t1), issue ei(t2)
    int r1 = (q < 2) ? s2 : ((s2 & ~(NNODES - 1)) | (d2 & (NNODES - 1)));
    const uint4* sp1 = (const uint4*)(zb + r1 * DLAT + (q & 1) * 32);
    g0 = sp1[0]; g1 = sp1[1]; g2 = sp1[2]; g3 = sp1[3];
    if (wave == 0) av = ((const float4*)attr)[tc1 * TILE + tid];
    s2 = ei[tc2 * TILE + e];
    d2 = ei[E_EDGES + tc2 * TILE + e];
  }
  bar_lds();   // buffer 0 staged & visible; prefetches still in flight

  int pp = 0;
  for (int tile = t0; ; ) {
    const unsigned short* Ar = A + pp * (TILE * KP);

    floatx4 acc[2][4];
#pragma unroll
    for (int mt = 0; mt < 2; ++mt)
#pragma unroll
      for (int nt = 0; nt < 4; ++nt)
        acc[mt][nt] = (floatx4){0.f, 0.f, 0.f, 0.f};

#pragma unroll
    for (int kk = 0; kk < 5; ++kk) {
      shortx8 afr[2];
#pragma unroll
      for (int mt = 0; mt < 2; ++mt)
        afr[mt] = *(const shortx8*)(Ar + (eh * 32 + mt * 16 + l15) * KP + kk * 32 + quad * 8);
#pragma unroll
      for (int mt = 0; mt < 2; ++mt)
#pragma unroll
        for (int nt = 0; nt < 4; ++nt)
          acc[mt][nt] = __builtin_amdgcn_mfma_f32_16x16x32_bf16(
              afr[mt], bfr[nt][kk], acc[mt][nt], 0, 0, 0);
    }

    const int tnext = tile + grid;
    const bool more = tnext < NTILES;
    if (more) {
      // stage already-fetched tile 'tnext' into the idle buffer
      // (safe: everyone finished reading it at the previous bar_lds)
      unsigned short* Aw = A + (pp ^ 1) * (TILE * KP);
      uint4* dst = (uint4*)(Aw + e * KP + q * 32);
      dst[0] = g0; dst[1] = g1; dst[2] = g2; dst[3] = g3;   // waits counted vmcnt on g*
      if (wave == 0) {
        ushort4 a0; a0.x = f2bf(av.x); a0.y = f2bf(av.y); a0.z = f2bf(av.z); a0.w = f2bf(av.w);
        *(ushort4*)(Aw + tid * KP + 128) = a0;
      }
      // prefetch gather(tnext+grid) using in-flight ei; issue ei two tiles ahead
      int tn1 = tnext + grid; if (tn1 > NTILES - 1) tn1 = NTILES - 1;
      int tn2 = tn1 + grid;  if (tn2 > NTILES - 1) tn2 = NTILES - 1;
      int r = (q < 2) ? s2 : ((s2 & ~(NNODES - 1)) | (d2 & (NNODES - 1)));
      const uint4* sp = (const uint4*)(zb + r * DLAT + (q & 1) * 32);
      g0 = sp[0]; g1 = sp[1]; g2 = sp[2]; g3 = sp[3];
      if (wave == 0) av = ((const float4*)attr)[tn1 * TILE + tid];
      s2 = ei[tn2 * TILE + e];
      d2 = ei[E_EDGES + tn2 * TILE + e];
    }

    // ---- epilogue for 'tile'
    if (!OUT) {
      // C/D layout: col = lane&15 (channel), row = quad*4 + reg (edge)
#pragma unroll
      for (int nt = 0; nt < 4; ++nt) {
        float s = 0.f, qq = 0.f;
#pragma unroll
        for (int mt = 0; mt < 2; ++mt)
#pragma unroll
          for (int r = 0; r < 4; ++r) {
            float h = acc[mt][nt][r];
            s += h; qq += h * h;
          }
        ssum[nt] += s; ssq[nt] += qq;
      }
    } else {
      float tpart[2][4];
#pragma unroll
      for (int mt = 0; mt < 2; ++mt)
#pragma unroll
        for (int r = 0; r < 4; ++r) {
          float t = 0.f;
#pragma unroll
          for (int nt = 0; nt < 4; ++nt) {
            float h = acc[mt][nt][r];
            float p = ea[nt] * h + ebb[nt];
            p = (p >= 0.f) ? p : 0.2f * p;
            t += p * ew2[nt];
          }
          t += __shfl_xor(t, 1);
          t += __shfl_xor(t, 2);
          t += __shfl_xor(t, 4);
          t += __shfl_xor(t, 8);   // t = sum over this wave's 64 channels
          tpart[mt][r] = t;
        }
      // combine the two channel-halves (nh=0/1 waves share the same edges)
      if (nh == 1 && l15 == 0) {
#pragma unroll
        for (int mt = 0; mt < 2; ++mt)
#pragma unroll
          for (int r = 0; r < 4; ++r)
            po[eh * 32 + mt * 16 + quad * 4 + r] = tpart[mt][r];
      }
      bar_lds();
      if (nh == 0 && l15 == 0) {
#pragma unroll
        for (int mt = 0; mt < 2; ++mt)
#pragma unroll
          for (int r = 0; r < 4; ++r) {
            int el = eh * 32 + mt * 16 + quad * 4 + r;
            out[tile * TILE + el] = tpart[mt][r] + po[el] + b2v;
          }
      }
    }

    if (!more) break;
    bar_lds();       // staged buffer visible to all; vmcnt prefetches keep flying
    pp ^= 1;
    tile = tnext;
  }

  if (!OUT) {
#pragma unroll
    for (int nt = 0; nt < 4; ++nt) {
      float s = ssum[nt], qq = ssq[nt];
      s += __shfl_xor(s, 16); s += __shfl_xor(s, 32);
      qq += __shfl_xor(qq, 16); qq += __shfl_xor(qq, 32);
      if (quad == 0) {
        atomicAdd(&s_sum[nh * 64 + nt * 16 + l15], s);
        atomicAdd(&s_sq [nh * 64 + nt * 16 + l15], qq);
      }
    }
    __syncthreads();
    float* dstc = gstats + (blockIdx.x & (NSPREAD - 1)) * 2 * HCH;
    if (tid < HCH)          atomicAdd(&dstc[tid], s_sum[tid]);
    else if (tid < 2 * HCH) atomicAdd(&dstc[tid], s_sq[tid - HCH]);
  }
}

// -------------------------------------------------------------- launch ----
extern "C" void kernel_launch(void* const* d_in, const int* in_sizes, int n_in,
                              void* d_out, int out_size, void* d_ws, size_t ws_size,
                              hipStream_t stream) {
  const float* z     = (const float*)d_in[0];
  const float* attr  = (const float*)d_in[1];
  const float* W1    = (const float*)d_in[2];
  const float* b1    = (const float*)d_in[3];
  const float* gamma = (const float*)d_in[4];
  const float* beta  = (const float*)d_in[5];
  const float* W2    = (const float*)d_in[6];
  const float* b2    = (const float*)d_in[7];
  const int*   ei    = (const int*)d_in[8];
  float* out = (float*)d_out;

  char* ws = (char*)d_ws;
  unsigned short* zb  = (unsigned short*)ws;                 // 8,388,608 B
  unsigned short* w1t = (unsigned short*)(ws + 8388608);     //    43,008 B
  float* gstats       = (float*)(ws + 8431616);              //     8,192 B

  k_prep<<<ZBLK + 2, 256, 0, stream>>>(z, W1, b1, zb, w1t, gstats);
  k_gemm<false><<<GRID_GEMM, 256, 0, stream>>>(zb, w1t, ei, attr, gstats,
                                               gamma, beta, W2, b2, nullptr);
  k_gemm<true><<<GRID_GEMM, 256, 0, stream>>>(zb, w1t, ei, attr, gstats,
                                              gamma, beta, W2, b2, out);
}